// Round 1
// baseline (12251.068 us; speedup 1.0000x reference)
//
#include <hip/hip_runtime.h>
#include <math.h>

#define NN 50000
#define NE 1600000
#define H  32
#define ED 16
#define FIN 23
#define NL 4

union F4 { float4 v; float f[4]; };

__device__ __forceinline__ float silu_f(float v) {
    return v * (1.0f / (1.0f + __expf(-v)));
}

// accumulate 4 consecutive m_in rows (one float4) into hid[32];
// w points at w1 + (row0)*H; weights are wave-uniform -> s_load + v_fmac v,s,v
__device__ __forceinline__ void acc4(float hid[H], float4 hv4, const float* __restrict__ w) {
    F4 u; u.v = hv4;
    #pragma unroll
    for (int jj = 0; jj < 4; ++jj) {
        float v = u.f[jj];
        #pragma unroll
        for (int k = 0; k < H; ++k) hid[k] = fmaf(v, w[jj * H + k], hid[k]);
    }
}

__global__ __launch_bounds__(256) void proj_kernel(
    const float* __restrict__ feat, const float* __restrict__ W,
    const float* __restrict__ b, float* __restrict__ h)
{
    int n = blockIdx.x * 256 + threadIdx.x;
    if (n >= NN) return;
    float acc[H];
    #pragma unroll
    for (int k = 0; k < H; ++k) acc[k] = b[k];
    #pragma unroll 1
    for (int j = 0; j < FIN; ++j) {
        float v = feat[n * FIN + j];
        const float* w = W + j * H;
        #pragma unroll
        for (int k = 0; k < H; ++k) acc[k] = fmaf(v, w[k], acc[k]);
    }
    float4* h4 = (float4*)(h + (size_t)n * H);
    #pragma unroll
    for (int k4 = 0; k4 < H / 4; ++k4) {
        float4 o;
        o.x = acc[4*k4+0]; o.y = acc[4*k4+1]; o.z = acc[4*k4+2]; o.w = acc[4*k4+3];
        h4[k4] = o;
    }
}

__global__ __launch_bounds__(256) void egnn_edge(
    const float* __restrict__ h, const float* __restrict__ x,
    const float* __restrict__ ea,
    const int* __restrict__ esrc, const int* __restrict__ edst,
    const float* __restrict__ w1, const float* __restrict__ b1,
    const float* __restrict__ w2, const float* __restrict__ b2,
    const float* __restrict__ xw1, const float* __restrict__ xb1,
    const float* __restrict__ xw2, const float* __restrict__ xb2,
    float* __restrict__ agg, float* __restrict__ dxo)
{
    int e = blockIdx.x * 256 + threadIdx.x;
    if (e >= NE) return;
    int s = esrc[e];
    int d = edst[e];

    float xi0 = x[3*s+0], xi1 = x[3*s+1], xi2 = x[3*s+2];
    float xj0 = x[3*d+0], xj1 = x[3*d+1], xj2 = x[3*d+2];
    float d0 = xj0 - xi0, d1 = xj1 - xi1, d2 = xj2 - xi2;
    float sq = d0*d0 + d1*d1 + d2*d2;
    float dist = sqrtf(sq + 1e-9f);

    float hid[H];
    #pragma unroll
    for (int k = 0; k < H; ++k) hid[k] = b1[k];

    const float4* h4 = (const float4*)h;
    // rows 0..31: h_i = h[src]
    #pragma unroll 1
    for (int j4 = 0; j4 < H / 4; ++j4)
        acc4(hid, h4[(size_t)s * (H/4) + j4], w1 + (j4 * 4) * H);
    // rows 32..63: h_j = h[dst]
    #pragma unroll 1
    for (int j4 = 0; j4 < H / 4; ++j4)
        acc4(hid, h4[(size_t)d * (H/4) + j4], w1 + (H + j4 * 4) * H);
    // rows 64..79: edge_attr
    const float4* ea4 = (const float4*)(ea + (size_t)e * ED);
    #pragma unroll 1
    for (int j4 = 0; j4 < ED / 4; ++j4)
        acc4(hid, ea4[j4], w1 + (2 * H + j4 * 4) * H);
    // row 80: dist
    {
        const float* w = w1 + (2 * H + ED) * H;
        #pragma unroll
        for (int k = 0; k < H; ++k) hid[k] = fmaf(dist, w[k], hid[k]);
    }

    // SiLU + second linear of phi_e  -> m_ij
    float m[H];
    #pragma unroll
    for (int k = 0; k < H; ++k) m[k] = b2[k];
    #pragma unroll
    for (int j = 0; j < H; ++j) {
        float v = silu_f(hid[j]);
        const float* w = w2 + j * H;
        #pragma unroll
        for (int k = 0; k < H; ++k) m[k] = fmaf(v, w[k], m[k]);
    }

    // scatter m_ij into agg[dst]
    {
        float* ad = agg + (size_t)d * H;
        #pragma unroll
        for (int k = 0; k < H; ++k) unsafeAtomicAdd(ad + k, m[k]);
    }

    // phi_x: Linear(H->H), SiLU, Linear(H->1)
    float gh[H];
    #pragma unroll
    for (int k = 0; k < H; ++k) gh[k] = xb1[k];
    #pragma unroll
    for (int j = 0; j < H; ++j) {
        float v = m[j];
        const float* w = xw1 + j * H;
        #pragma unroll
        for (int k = 0; k < H; ++k) gh[k] = fmaf(v, w[k], gh[k]);
    }
    float gate = xb2[0];
    #pragma unroll
    for (int j = 0; j < H; ++j) gate = fmaf(silu_f(gh[j]), xw2[j], gate);

    float dirn = sqrtf(sq) + 1e-9f;   // norm(diff) + eps (eps OUTSIDE sqrt here)
    float scale = gate / dirn;
    float* dd = dxo + (size_t)d * 3;
    unsafeAtomicAdd(dd + 0, d0 * scale);
    unsafeAtomicAdd(dd + 1, d1 * scale);
    unsafeAtomicAdd(dd + 2, d2 * scale);
}

__global__ __launch_bounds__(256) void egnn_node(
    const float* __restrict__ h, const float* __restrict__ agg,
    const float* __restrict__ xin, const float* __restrict__ dxin,
    const float* __restrict__ w1, const float* __restrict__ b1,
    const float* __restrict__ w2, const float* __restrict__ b2,
    const float* __restrict__ lng, const float* __restrict__ lnb,
    float* __restrict__ hout, float* __restrict__ xout)
{
    int n = blockIdx.x * 256 + threadIdx.x;
    if (n >= NN) return;
    const float4* h4 = (const float4*)(h + (size_t)n * H);
    const float4* a4 = (const float4*)(agg + (size_t)n * H);

    float hid[H];
    #pragma unroll
    for (int k = 0; k < H; ++k) hid[k] = b1[k];
    #pragma unroll 1
    for (int j4 = 0; j4 < H / 4; ++j4)
        acc4(hid, h4[j4], w1 + (j4 * 4) * H);
    #pragma unroll 1
    for (int j4 = 0; j4 < H / 4; ++j4)
        acc4(hid, a4[j4], w1 + (H + j4 * 4) * H);

    float dh[H];
    #pragma unroll
    for (int k = 0; k < H; ++k) dh[k] = b2[k];
    #pragma unroll
    for (int j = 0; j < H; ++j) {
        float v = silu_f(hid[j]);
        const float* w = w2 + j * H;
        #pragma unroll
        for (int k = 0; k < H; ++k) dh[k] = fmaf(v, w[k], dh[k]);
    }

    // residual + LayerNorm
    float y[H];
    #pragma unroll
    for (int k4 = 0; k4 < H / 4; ++k4) {
        F4 u; u.v = h4[k4];
        #pragma unroll
        for (int jj = 0; jj < 4; ++jj) y[4*k4+jj] = u.f[jj] + dh[4*k4+jj];
    }
    float mu = 0.0f;
    #pragma unroll
    for (int k = 0; k < H; ++k) mu += y[k];
    mu *= (1.0f / H);
    float var = 0.0f;
    #pragma unroll
    for (int k = 0; k < H; ++k) { float t = y[k] - mu; var += t * t; }
    var *= (1.0f / H);
    float rstd = rsqrtf(var + 1e-5f);

    float4* ho4 = (float4*)(hout + (size_t)n * H);
    #pragma unroll
    for (int k4 = 0; k4 < H / 4; ++k4) {
        float4 o;
        o.x = (y[4*k4+0] - mu) * rstd * lng[4*k4+0] + lnb[4*k4+0];
        o.y = (y[4*k4+1] - mu) * rstd * lng[4*k4+1] + lnb[4*k4+1];
        o.z = (y[4*k4+2] - mu) * rstd * lng[4*k4+2] + lnb[4*k4+2];
        o.w = (y[4*k4+3] - mu) * rstd * lng[4*k4+3] + lnb[4*k4+3];
        ho4[k4] = o;
    }

    xout[3*n+0] = xin[3*n+0] + dxin[3*n+0];
    xout[3*n+1] = xin[3*n+1] + dxin[3*n+1];
    xout[3*n+2] = xin[3*n+2] + dxin[3*n+2];
}

extern "C" void kernel_launch(void* const* d_in, const int* in_sizes, int n_in,
                              void* d_out, int out_size, void* d_ws, size_t ws_size,
                              hipStream_t stream) {
    const float* node_pos  = (const float*)d_in[0];
    const float* node_feat = (const float*)d_in[1];
    const float* edge_attr = (const float*)d_in[2];
    const float* proj_w    = (const float*)d_in[3];
    const float* proj_b    = (const float*)d_in[4];
    const float* pe_w1     = (const float*)d_in[5];
    const float* pe_b1     = (const float*)d_in[6];
    const float* pe_w2     = (const float*)d_in[7];
    const float* pe_b2     = (const float*)d_in[8];
    const float* ph_w1     = (const float*)d_in[9];
    const float* ph_b1     = (const float*)d_in[10];
    const float* ph_w2     = (const float*)d_in[11];
    const float* ph_b2     = (const float*)d_in[12];
    const float* px_w1     = (const float*)d_in[13];
    const float* px_b1     = (const float*)d_in[14];
    const float* px_w2     = (const float*)d_in[15];
    const float* px_b2     = (const float*)d_in[16];
    const float* ln_g      = (const float*)d_in[17];
    const float* ln_b      = (const float*)d_in[18];
    const int*   eidx      = (const int*)d_in[19];
    const int*   esrc      = eidx;
    const int*   edst      = eidx + NE;

    float* out_h = (float*)d_out;
    float* out_x = out_h + (size_t)NN * H;

    float* h_a = (float*)d_ws;
    float* h_b = h_a + (size_t)NN * H;
    float* x_a = h_b + (size_t)NN * H;
    float* x_b = x_a + (size_t)NN * 3;
    float* agg = x_b + (size_t)NN * 3;
    float* dxb = agg + (size_t)NN * H;   // agg and dxb adjacent -> single memset

    dim3 nblk((NN + 255) / 256), eblk((NE + 255) / 256);

    proj_kernel<<<nblk, 256, 0, stream>>>(node_feat, proj_w, proj_b, h_a);

    const float* hcur = h_a;
    const float* xcur = node_pos;
    float* hbufs[2] = { h_b, h_a };
    float* xbufs[2] = { x_a, x_b };

    for (int l = 0; l < NL; ++l) {
        hipMemsetAsync(agg, 0, (size_t)NN * (H + 3) * sizeof(float), stream);
        egnn_edge<<<eblk, 256, 0, stream>>>(hcur, xcur, edge_attr, esrc, edst,
            pe_w1 + (size_t)l * (2*H + ED + 1) * H, pe_b1 + l * H,
            pe_w2 + (size_t)l * H * H,             pe_b2 + l * H,
            px_w1 + (size_t)l * H * H,             px_b1 + l * H,
            px_w2 + (size_t)l * H,                 px_b2 + l,
            agg, dxb);
        float* ho = (l == NL - 1) ? out_h : hbufs[l & 1];
        float* xo = (l == NL - 1) ? out_x : xbufs[l & 1];
        egnn_node<<<nblk, 256, 0, stream>>>(hcur, agg, xcur, dxb,
            ph_w1 + (size_t)l * 2 * H * H, ph_b1 + l * H,
            ph_w2 + (size_t)l * H * H,     ph_b2 + l * H,
            ln_g + l * H, ln_b + l * H, ho, xo);
        hcur = ho;
        xcur = xo;
    }
}

// Round 2
// 1949.249 us; speedup vs baseline: 6.2850x; 6.2850x over previous
//
#include <hip/hip_runtime.h>
#include <math.h>

#define NN 50000
#define NE 1600000
#define H  32
#define ED 16
#define FIN 23
#define NL 4

union F4 { float4 v; float f[4]; };

__device__ __forceinline__ float silu_f(float v) {
    return v * (1.0f / (1.0f + __expf(-v)));
}

__device__ __forceinline__ void acc4(float hid[H], float4 hv4, const float* __restrict__ w) {
    F4 u; u.v = hv4;
    #pragma unroll
    for (int jj = 0; jj < 4; ++jj) {
        float v = u.f[jj];
        #pragma unroll
        for (int k = 0; k < H; ++k) hid[k] = fmaf(v, w[jj * H + k], hid[k]);
    }
}

__global__ __launch_bounds__(256) void proj_kernel(
    const float* __restrict__ feat, const float* __restrict__ W,
    const float* __restrict__ b, float* __restrict__ h)
{
    int n = blockIdx.x * 256 + threadIdx.x;
    if (n >= NN) return;
    float acc[H];
    #pragma unroll
    for (int k = 0; k < H; ++k) acc[k] = b[k];
    #pragma unroll 1
    for (int j = 0; j < FIN; ++j) {
        float v = feat[n * FIN + j];
        const float* w = W + j * H;
        #pragma unroll
        for (int k = 0; k < H; ++k) acc[k] = fmaf(v, w[k], acc[k]);
    }
    float4* h4 = (float4*)(h + (size_t)n * H);
    #pragma unroll
    for (int k4 = 0; k4 < H / 4; ++k4) {
        float4 o;
        o.x = acc[4*k4+0]; o.y = acc[4*k4+1]; o.z = acc[4*k4+2]; o.w = acc[4*k4+3];
        h4[k4] = o;
    }
}

// ---------------- CSR build (once per call) ----------------

__global__ __launch_bounds__(256) void k_hist(
    const int* __restrict__ edst, int* __restrict__ cnt, int* __restrict__ rank)
{
    int e = blockIdx.x * 256 + threadIdx.x;
    if (e >= NE) return;
    rank[e] = atomicAdd(&cnt[edst[e]], 1);
}

__global__ __launch_bounds__(1024) void k_scan(
    const int* __restrict__ cnt, int* __restrict__ rs)
{
    __shared__ int wsum[16];
    __shared__ int s_carry;
    int t = threadIdx.x;
    int lane = t & 63, wid = t >> 6;
    if (t == 0) s_carry = 0;
    __syncthreads();
    for (int base = 0; base < NN; base += 1024) {
        int i = base + t;
        int v = (i < NN) ? cnt[i] : 0;
        int incl = v;
        #pragma unroll
        for (int off = 1; off < 64; off <<= 1) {
            int u = __shfl_up(incl, off, 64);
            if (lane >= off) incl += u;
        }
        if (lane == 63) wsum[wid] = incl;
        __syncthreads();
        int wpre = 0;
        #pragma unroll
        for (int w = 0; w < 16; ++w) { int ws = wsum[w]; wpre += (w < wid) ? ws : 0; }
        int carry = s_carry;
        if (i < NN) rs[i] = carry + wpre + incl - v;   // exclusive
        __syncthreads();
        if (t == 1023) s_carry = carry + wpre + incl;
        __syncthreads();
    }
    if (t == 0) rs[NN] = s_carry;
}

__global__ __launch_bounds__(256) void k_scatter(
    const int* __restrict__ edst, const int* __restrict__ rank,
    const int* __restrict__ rs, int* __restrict__ eid)
{
    int e = blockIdx.x * 256 + threadIdx.x;
    if (e >= NE) return;
    eid[rs[edst[e]] + rank[e]] = e;
}

// ---------------- sorted edge kernel: no atomics, coalesced writes ----------------

__global__ __launch_bounds__(256) void egnn_edge2(
    const float* __restrict__ h, const float* __restrict__ x,
    const float* __restrict__ ea,
    const int* __restrict__ esrc, const int* __restrict__ edst,
    const int* __restrict__ eid,
    const float* __restrict__ w1, const float* __restrict__ b1,
    const float* __restrict__ w2, const float* __restrict__ b2,
    const float* __restrict__ xw1, const float* __restrict__ xb1,
    const float* __restrict__ xw2, const float* __restrict__ xb2,
    float* __restrict__ msg, float* __restrict__ cbuf)
{
    int slot = blockIdx.x * 256 + threadIdx.x;
    if (slot >= NE) return;
    int e = eid[slot];
    int s = esrc[e];
    int d = edst[e];

    float xi0 = x[3*s+0], xi1 = x[3*s+1], xi2 = x[3*s+2];
    float xj0 = x[3*d+0], xj1 = x[3*d+1], xj2 = x[3*d+2];
    float d0 = xj0 - xi0, d1 = xj1 - xi1, d2 = xj2 - xi2;
    float sq = d0*d0 + d1*d1 + d2*d2;
    float dist = sqrtf(sq + 1e-9f);

    float hid[H];
    #pragma unroll
    for (int k = 0; k < H; ++k) hid[k] = b1[k];

    const float4* h4 = (const float4*)h;
    #pragma unroll 1
    for (int j4 = 0; j4 < H / 4; ++j4)
        acc4(hid, h4[(size_t)s * (H/4) + j4], w1 + (j4 * 4) * H);
    #pragma unroll 1
    for (int j4 = 0; j4 < H / 4; ++j4)
        acc4(hid, h4[(size_t)d * (H/4) + j4], w1 + (H + j4 * 4) * H);
    const float4* ea4 = (const float4*)(ea + (size_t)e * ED);
    #pragma unroll 1
    for (int j4 = 0; j4 < ED / 4; ++j4)
        acc4(hid, ea4[j4], w1 + (2 * H + j4 * 4) * H);
    {
        const float* w = w1 + (2 * H + ED) * H;
        #pragma unroll
        for (int k = 0; k < H; ++k) hid[k] = fmaf(dist, w[k], hid[k]);
    }

    float m[H];
    #pragma unroll
    for (int k = 0; k < H; ++k) m[k] = b2[k];
    #pragma unroll
    for (int j = 0; j < H; ++j) {
        float v = silu_f(hid[j]);
        const float* w = w2 + j * H;
        #pragma unroll
        for (int k = 0; k < H; ++k) m[k] = fmaf(v, w[k], m[k]);
    }

    float4* m4 = (float4*)(msg + (size_t)slot * H);
    #pragma unroll
    for (int k4 = 0; k4 < H / 4; ++k4) {
        float4 o;
        o.x = m[4*k4+0]; o.y = m[4*k4+1]; o.z = m[4*k4+2]; o.w = m[4*k4+3];
        m4[k4] = o;
    }

    float gh[H];
    #pragma unroll
    for (int k = 0; k < H; ++k) gh[k] = xb1[k];
    #pragma unroll
    for (int j = 0; j < H; ++j) {
        float v = m[j];
        const float* w = xw1 + j * H;
        #pragma unroll
        for (int k = 0; k < H; ++k) gh[k] = fmaf(v, w[k], gh[k]);
    }
    float gate = xb2[0];
    #pragma unroll
    for (int j = 0; j < H; ++j) gate = fmaf(silu_f(gh[j]), xw2[j], gate);

    float dirn = sqrtf(sq) + 1e-9f;
    float scale = gate / dirn;
    float4 c4;
    c4.x = d0 * scale; c4.y = d1 * scale; c4.z = d2 * scale; c4.w = 0.0f;
    ((float4*)cbuf)[slot] = c4;
}

// ---------------- node kernel: gather-aggregate + phi_h + LN + x ----------------

__global__ __launch_bounds__(256) void egnn_node2(
    const float* __restrict__ h, const float* __restrict__ xin,
    const float* __restrict__ msg, const float* __restrict__ cbuf,
    const int* __restrict__ rs,
    const float* __restrict__ w1, const float* __restrict__ b1,
    const float* __restrict__ w2, const float* __restrict__ b2,
    const float* __restrict__ lng, const float* __restrict__ lnb,
    float* __restrict__ hout, float* __restrict__ xout)
{
    __shared__ float smH[8][H];
    __shared__ float smA[8][H];
    __shared__ float smS[8][H];
    int nn = threadIdx.x >> 5;
    int lane = threadIdx.x & 31;
    int g = blockIdx.x * 8 + nn;          // grid is exactly NN/8 = 6250 blocks

    int start = rs[g], end = rs[g + 1];

    float aggk = 0.0f;
    #pragma unroll 1
    for (int sl = start; sl < end; ++sl)
        aggk += msg[(size_t)sl * H + lane];

    float cp = 0.0f;
    #pragma unroll 1
    for (int sl = start + (lane >> 2); sl < end; sl += 8)
        cp += cbuf[(size_t)sl * 4 + (lane & 3)];
    cp += __shfl_xor(cp, 4, 32);
    cp += __shfl_xor(cp, 8, 32);
    cp += __shfl_xor(cp, 16, 32);

    float hk = h[(size_t)g * H + lane];
    smH[nn][lane] = hk;
    smA[nn][lane] = aggk;
    __syncthreads();

    float hid = b1[lane];
    #pragma unroll
    for (int j = 0; j < H; ++j) hid = fmaf(smH[nn][j], w1[j * H + lane], hid);
    #pragma unroll
    for (int j = 0; j < H; ++j) hid = fmaf(smA[nn][j], w1[(H + j) * H + lane], hid);

    smS[nn][lane] = silu_f(hid);
    __syncthreads();

    float dh = b2[lane];
    #pragma unroll
    for (int j = 0; j < H; ++j) dh = fmaf(smS[nn][j], w2[j * H + lane], dh);

    float y = hk + dh;
    float mu = y;
    mu += __shfl_xor(mu, 1, 32);  mu += __shfl_xor(mu, 2, 32);
    mu += __shfl_xor(mu, 4, 32);  mu += __shfl_xor(mu, 8, 32);
    mu += __shfl_xor(mu, 16, 32);
    mu *= (1.0f / H);
    float t = y - mu;
    float var = t * t;
    var += __shfl_xor(var, 1, 32);  var += __shfl_xor(var, 2, 32);
    var += __shfl_xor(var, 4, 32);  var += __shfl_xor(var, 8, 32);
    var += __shfl_xor(var, 16, 32);
    var *= (1.0f / H);
    float rstd = rsqrtf(var + 1e-5f);

    hout[(size_t)g * H + lane] = t * rstd * lng[lane] + lnb[lane];
    if (lane < 3)
        xout[(size_t)g * 3 + lane] = xin[(size_t)g * 3 + lane] + cp;
}

// ---------------- fallback (atomic) kernels, used only if ws too small ----------------

__global__ __launch_bounds__(256) void egnn_edge_atomic(
    const float* __restrict__ h, const float* __restrict__ x,
    const float* __restrict__ ea,
    const int* __restrict__ esrc, const int* __restrict__ edst,
    const float* __restrict__ w1, const float* __restrict__ b1,
    const float* __restrict__ w2, const float* __restrict__ b2,
    const float* __restrict__ xw1, const float* __restrict__ xb1,
    const float* __restrict__ xw2, const float* __restrict__ xb2,
    float* __restrict__ agg, float* __restrict__ dxo)
{
    int e = blockIdx.x * 256 + threadIdx.x;
    if (e >= NE) return;
    int s = esrc[e];
    int d = edst[e];
    float xi0 = x[3*s+0], xi1 = x[3*s+1], xi2 = x[3*s+2];
    float xj0 = x[3*d+0], xj1 = x[3*d+1], xj2 = x[3*d+2];
    float d0 = xj0 - xi0, d1 = xj1 - xi1, d2 = xj2 - xi2;
    float sq = d0*d0 + d1*d1 + d2*d2;
    float dist = sqrtf(sq + 1e-9f);
    float hid[H];
    #pragma unroll
    for (int k = 0; k < H; ++k) hid[k] = b1[k];
    const float4* h4 = (const float4*)h;
    #pragma unroll 1
    for (int j4 = 0; j4 < H / 4; ++j4)
        acc4(hid, h4[(size_t)s * (H/4) + j4], w1 + (j4 * 4) * H);
    #pragma unroll 1
    for (int j4 = 0; j4 < H / 4; ++j4)
        acc4(hid, h4[(size_t)d * (H/4) + j4], w1 + (H + j4 * 4) * H);
    const float4* ea4 = (const float4*)(ea + (size_t)e * ED);
    #pragma unroll 1
    for (int j4 = 0; j4 < ED / 4; ++j4)
        acc4(hid, ea4[j4], w1 + (2 * H + j4 * 4) * H);
    {
        const float* w = w1 + (2 * H + ED) * H;
        #pragma unroll
        for (int k = 0; k < H; ++k) hid[k] = fmaf(dist, w[k], hid[k]);
    }
    float m[H];
    #pragma unroll
    for (int k = 0; k < H; ++k) m[k] = b2[k];
    #pragma unroll
    for (int j = 0; j < H; ++j) {
        float v = silu_f(hid[j]);
        const float* w = w2 + j * H;
        #pragma unroll
        for (int k = 0; k < H; ++k) m[k] = fmaf(v, w[k], m[k]);
    }
    {
        float* ad = agg + (size_t)d * H;
        #pragma unroll
        for (int k = 0; k < H; ++k) unsafeAtomicAdd(ad + k, m[k]);
    }
    float gh[H];
    #pragma unroll
    for (int k = 0; k < H; ++k) gh[k] = xb1[k];
    #pragma unroll
    for (int j = 0; j < H; ++j) {
        float v = m[j];
        const float* w = xw1 + j * H;
        #pragma unroll
        for (int k = 0; k < H; ++k) gh[k] = fmaf(v, w[k], gh[k]);
    }
    float gate = xb2[0];
    #pragma unroll
    for (int j = 0; j < H; ++j) gate = fmaf(silu_f(gh[j]), xw2[j], gate);
    float dirn = sqrtf(sq) + 1e-9f;
    float scale = gate / dirn;
    float* dd = dxo + (size_t)d * 3;
    unsafeAtomicAdd(dd + 0, d0 * scale);
    unsafeAtomicAdd(dd + 1, d1 * scale);
    unsafeAtomicAdd(dd + 2, d2 * scale);
}

__global__ __launch_bounds__(256) void egnn_node_atomic(
    const float* __restrict__ h, const float* __restrict__ agg,
    const float* __restrict__ xin, const float* __restrict__ dxin,
    const float* __restrict__ w1, const float* __restrict__ b1,
    const float* __restrict__ w2, const float* __restrict__ b2,
    const float* __restrict__ lng, const float* __restrict__ lnb,
    float* __restrict__ hout, float* __restrict__ xout)
{
    int n = blockIdx.x * 256 + threadIdx.x;
    if (n >= NN) return;
    const float4* h4 = (const float4*)(h + (size_t)n * H);
    const float4* a4 = (const float4*)(agg + (size_t)n * H);
    float hid[H];
    #pragma unroll
    for (int k = 0; k < H; ++k) hid[k] = b1[k];
    #pragma unroll 1
    for (int j4 = 0; j4 < H / 4; ++j4)
        acc4(hid, h4[j4], w1 + (j4 * 4) * H);
    #pragma unroll 1
    for (int j4 = 0; j4 < H / 4; ++j4)
        acc4(hid, a4[j4], w1 + (H + j4 * 4) * H);
    float dh[H];
    #pragma unroll
    for (int k = 0; k < H; ++k) dh[k] = b2[k];
    #pragma unroll
    for (int j = 0; j < H; ++j) {
        float v = silu_f(hid[j]);
        const float* w = w2 + j * H;
        #pragma unroll
        for (int k = 0; k < H; ++k) dh[k] = fmaf(v, w[k], dh[k]);
    }
    float y[H];
    #pragma unroll
    for (int k4 = 0; k4 < H / 4; ++k4) {
        F4 u; u.v = h4[k4];
        #pragma unroll
        for (int jj = 0; jj < 4; ++jj) y[4*k4+jj] = u.f[jj] + dh[4*k4+jj];
    }
    float mu = 0.0f;
    #pragma unroll
    for (int k = 0; k < H; ++k) mu += y[k];
    mu *= (1.0f / H);
    float var = 0.0f;
    #pragma unroll
    for (int k = 0; k < H; ++k) { float t = y[k] - mu; var += t * t; }
    var *= (1.0f / H);
    float rstd = rsqrtf(var + 1e-5f);
    float4* ho4 = (float4*)(hout + (size_t)n * H);
    #pragma unroll
    for (int k4 = 0; k4 < H / 4; ++k4) {
        float4 o;
        o.x = (y[4*k4+0] - mu) * rstd * lng[4*k4+0] + lnb[4*k4+0];
        o.y = (y[4*k4+1] - mu) * rstd * lng[4*k4+1] + lnb[4*k4+1];
        o.z = (y[4*k4+2] - mu) * rstd * lng[4*k4+2] + lnb[4*k4+2];
        o.w = (y[4*k4+3] - mu) * rstd * lng[4*k4+3] + lnb[4*k4+3];
        ho4[k4] = o;
    }
    xout[3*n+0] = xin[3*n+0] + dxin[3*n+0];
    xout[3*n+1] = xin[3*n+1] + dxin[3*n+1];
    xout[3*n+2] = xin[3*n+2] + dxin[3*n+2];
}

extern "C" void kernel_launch(void* const* d_in, const int* in_sizes, int n_in,
                              void* d_out, int out_size, void* d_ws, size_t ws_size,
                              hipStream_t stream) {
    const float* node_pos  = (const float*)d_in[0];
    const float* node_feat = (const float*)d_in[1];
    const float* edge_attr = (const float*)d_in[2];
    const float* proj_w    = (const float*)d_in[3];
    const float* proj_b    = (const float*)d_in[4];
    const float* pe_w1     = (const float*)d_in[5];
    const float* pe_b1     = (const float*)d_in[6];
    const float* pe_w2     = (const float*)d_in[7];
    const float* pe_b2     = (const float*)d_in[8];
    const float* ph_w1     = (const float*)d_in[9];
    const float* ph_b1     = (const float*)d_in[10];
    const float* ph_w2     = (const float*)d_in[11];
    const float* ph_b2     = (const float*)d_in[12];
    const float* px_w1     = (const float*)d_in[13];
    const float* px_b1     = (const float*)d_in[14];
    const float* px_w2     = (const float*)d_in[15];
    const float* px_b2     = (const float*)d_in[16];
    const float* ln_g      = (const float*)d_in[17];
    const float* ln_b      = (const float*)d_in[18];
    const int*   eidx      = (const int*)d_in[19];
    const int*   esrc      = eidx;
    const int*   edst      = eidx + NE;

    float* out_h = (float*)d_out;
    float* out_x = out_h + (size_t)NN * H;

    dim3 nblk((NN + 255) / 256), eblk((NE + 255) / 256);

    size_t off = 0;
    float* msg  = (float*)d_ws;               off += (size_t)NE * H;
    float* cbuf = (float*)d_ws + off;         off += (size_t)NE * 4;
    float* h_a  = (float*)d_ws + off;         off += (size_t)NN * H;
    float* h_b  = (float*)d_ws + off;         off += (size_t)NN * H;
    float* x_a  = (float*)d_ws + off;         off += (size_t)NN * 3;
    float* x_b  = (float*)d_ws + off;         off += (size_t)NN * 3;
    int*   cnt  = (int*)((float*)d_ws + off); off += NN;
    int*   rs   = (int*)((float*)d_ws + off); off += NN + 4;
    int*   rank = (int*)((float*)d_ws + off); off += NE;
    int*   eid  = (int*)((float*)d_ws + off); off += NE;
    size_t need = off * sizeof(float);

    if (ws_size >= need) {
        hipMemsetAsync(cnt, 0, NN * sizeof(int), stream);
        k_hist<<<eblk, 256, 0, stream>>>(edst, cnt, rank);
        k_scan<<<1, 1024, 0, stream>>>(cnt, rs);
        k_scatter<<<eblk, 256, 0, stream>>>(edst, rank, rs, eid);

        proj_kernel<<<nblk, 256, 0, stream>>>(node_feat, proj_w, proj_b, h_a);

        const float* hcur = h_a;
        const float* xcur = node_pos;
        float* hbufs[2] = { h_b, h_a };
        float* xbufs[2] = { x_a, x_b };

        for (int l = 0; l < NL; ++l) {
            egnn_edge2<<<eblk, 256, 0, stream>>>(hcur, xcur, edge_attr, esrc, edst, eid,
                pe_w1 + (size_t)l * (2*H + ED + 1) * H, pe_b1 + l * H,
                pe_w2 + (size_t)l * H * H,             pe_b2 + l * H,
                px_w1 + (size_t)l * H * H,             px_b1 + l * H,
                px_w2 + (size_t)l * H,                 px_b2 + l,
                msg, cbuf);
            float* ho = (l == NL - 1) ? out_h : hbufs[l & 1];
            float* xo = (l == NL - 1) ? out_x : xbufs[l & 1];
            egnn_node2<<<dim3(NN / 8), 256, 0, stream>>>(hcur, xcur, msg, cbuf, rs,
                ph_w1 + (size_t)l * 2 * H * H, ph_b1 + l * H,
                ph_w2 + (size_t)l * H * H,     ph_b2 + l * H,
                ln_g + l * H, ln_b + l * H, ho, xo);
            hcur = ho;
            xcur = xo;
        }
    } else {
        float* h_a2 = (float*)d_ws;
        float* h_b2 = h_a2 + (size_t)NN * H;
        float* x_a2 = h_b2 + (size_t)NN * H;
        float* x_b2 = x_a2 + (size_t)NN * 3;
        float* agg  = x_b2 + (size_t)NN * 3;
        float* dxb  = agg + (size_t)NN * H;

        proj_kernel<<<nblk, 256, 0, stream>>>(node_feat, proj_w, proj_b, h_a2);

        const float* hcur = h_a2;
        const float* xcur = node_pos;
        float* hbufs[2] = { h_b2, h_a2 };
        float* xbufs[2] = { x_a2, x_b2 };

        for (int l = 0; l < NL; ++l) {
            hipMemsetAsync(agg, 0, (size_t)NN * (H + 3) * sizeof(float), stream);
            egnn_edge_atomic<<<eblk, 256, 0, stream>>>(hcur, xcur, edge_attr, esrc, edst,
                pe_w1 + (size_t)l * (2*H + ED + 1) * H, pe_b1 + l * H,
                pe_w2 + (size_t)l * H * H,             pe_b2 + l * H,
                px_w1 + (size_t)l * H * H,             px_b1 + l * H,
                px_w2 + (size_t)l * H,                 px_b2 + l,
                agg, dxb);
            float* ho = (l == NL - 1) ? out_h : hbufs[l & 1];
            float* xo = (l == NL - 1) ? out_x : xbufs[l & 1];
            egnn_node_atomic<<<nblk, 256, 0, stream>>>(hcur, agg, xcur, dxb,
                ph_w1 + (size_t)l * 2 * H * H, ph_b1 + l * H,
                ph_w2 + (size_t)l * H * H,     ph_b2 + l * H,
                ln_g + l * H, ln_b + l * H, ho, xo);
            hcur = ho;
            xcur = xo;
        }
    }
}

// Round 4
// 1331.239 us; speedup vs baseline: 9.2028x; 1.4642x over previous
//
#include <hip/hip_runtime.h>
#include <math.h>

#define NN 50000
#define NE 1600000
#define H  32
#define ED 16
#define FIN 23
#define NL 4

union F4 { float4 v; float f[4]; };

__device__ __forceinline__ float silu_f(float v) {
    return v * (1.0f / (1.0f + __expf(-v)));
}

// hid += (4 rows of W) dot (4 input vals in hv4); W rows wave-uniform -> s_load + v_fmac
__device__ __forceinline__ void acc4(float hid[H], float4 hv4, const float* __restrict__ w) {
    F4 u; u.v = hv4;
    #pragma unroll
    for (int jj = 0; jj < 4; ++jj) {
        float v = u.f[jj];
        #pragma unroll
        for (int k = 0; k < H; ++k) hid[k] = fmaf(v, w[jj * H + k], hid[k]);
    }
}

// ---------------- CSR build (once per call) ----------------

__global__ __launch_bounds__(256) void k_hist(
    const int* __restrict__ edst, int* __restrict__ cnt, int* __restrict__ rank)
{
    int e = blockIdx.x * 256 + threadIdx.x;
    if (e >= NE) return;
    rank[e] = atomicAdd(&cnt[edst[e]], 1);
}

__global__ __launch_bounds__(1024) void k_scan(
    const int* __restrict__ cnt, int* __restrict__ rs)
{
    __shared__ int wsum[16];
    __shared__ int s_carry;
    int t = threadIdx.x;
    int lane = t & 63, wid = t >> 6;
    if (t == 0) s_carry = 0;
    __syncthreads();
    for (int base = 0; base < NN; base += 1024) {
        int i = base + t;
        int v = (i < NN) ? cnt[i] : 0;
        int incl = v;
        #pragma unroll
        for (int off = 1; off < 64; off <<= 1) {
            int u = __shfl_up(incl, off, 64);
            if (lane >= off) incl += u;
        }
        if (lane == 63) wsum[wid] = incl;
        __syncthreads();
        int wpre = 0;
        #pragma unroll
        for (int w = 0; w < 16; ++w) { int ws = wsum[w]; wpre += (w < wid) ? ws : 0; }
        int carry = s_carry;
        if (i < NN) rs[i] = carry + wpre + incl - v;   // exclusive
        __syncthreads();
        if (t == 1023) s_carry = carry + wpre + incl;
        __syncthreads();
    }
    if (t == 0) rs[NN] = s_carry;
}

__global__ __launch_bounds__(256) void k_scatter(
    const int* __restrict__ edst, const int* __restrict__ rank,
    const int* __restrict__ rs, int* __restrict__ eid)
{
    int e = blockIdx.x * 256 + threadIdx.x;
    if (e >= NE) return;
    eid[rs[edst[e]] + rank[e]] = e;
}

// permute edge_attr + (src,dst) into dst-sorted slot order (once; reused all layers)
__global__ __launch_bounds__(256) void k_permute(
    const int* __restrict__ eid, const float* __restrict__ ea,
    const int* __restrict__ esrc, const int* __restrict__ edst,
    float* __restrict__ ea_s, int2* __restrict__ sd_s)
{
    int slot = blockIdx.x * 256 + threadIdx.x;
    if (slot >= NE) return;
    int e = eid[slot];
    const float4* src4 = (const float4*)(ea + (size_t)e * ED);
    float4* dst4 = (float4*)(ea_s + (size_t)slot * ED);
    #pragma unroll
    for (int j = 0; j < ED / 4; ++j) dst4[j] = src4[j];
    int2 sd; sd.x = esrc[e]; sd.y = edst[e];
    sd_s[slot] = sd;
}

// ---------------- input projection + layer-0 node pre-projections ----------------

__global__ __launch_bounds__(256) void proj2(
    const float* __restrict__ feat, const float* __restrict__ W,
    const float* __restrict__ bias, const float* __restrict__ pew1,
    float* __restrict__ h, float* __restrict__ a, float* __restrict__ b)
{
    int n = blockIdx.x * 256 + threadIdx.x;
    if (n >= NN) return;
    float acc[H];
    #pragma unroll
    for (int k = 0; k < H; ++k) acc[k] = bias[k];
    #pragma unroll 1
    for (int j = 0; j < FIN; ++j) {
        float v = feat[n * FIN + j];
        const float* w = W + j * H;
        #pragma unroll
        for (int k = 0; k < H; ++k) acc[k] = fmaf(v, w[k], acc[k]);
    }
    float4* h4 = (float4*)(h + (size_t)n * H);
    #pragma unroll
    for (int k4 = 0; k4 < H / 4; ++k4) {
        float4 o;
        o.x = acc[4*k4+0]; o.y = acc[4*k4+1]; o.z = acc[4*k4+2]; o.w = acc[4*k4+3];
        h4[k4] = o;
    }
    // a = h @ pew1[rows 0..31], b = h @ pew1[rows 32..63]
    float pa[H];
    #pragma unroll
    for (int k = 0; k < H; ++k) pa[k] = 0.0f;
    #pragma unroll 1
    for (int j = 0; j < H; ++j) {
        float v = acc[j];
        const float* w = pew1 + j * H;
        #pragma unroll
        for (int k = 0; k < H; ++k) pa[k] = fmaf(v, w[k], pa[k]);
    }
    float4* a4 = (float4*)(a + (size_t)n * H);
    #pragma unroll
    for (int k4 = 0; k4 < H / 4; ++k4) {
        float4 o;
        o.x = pa[4*k4+0]; o.y = pa[4*k4+1]; o.z = pa[4*k4+2]; o.w = pa[4*k4+3];
        a4[k4] = o;
    }
    #pragma unroll
    for (int k = 0; k < H; ++k) pa[k] = 0.0f;
    #pragma unroll 1
    for (int j = 0; j < H; ++j) {
        float v = acc[j];
        const float* w = pew1 + (H + j) * H;
        #pragma unroll
        for (int k = 0; k < H; ++k) pa[k] = fmaf(v, w[k], pa[k]);
    }
    float4* b4 = (float4*)(b + (size_t)n * H);
    #pragma unroll
    for (int k4 = 0; k4 < H / 4; ++k4) {
        float4 o;
        o.x = pa[4*k4+0]; o.y = pa[4*k4+1]; o.z = pa[4*k4+2]; o.w = pa[4*k4+3];
        b4[k4] = o;
    }
}

// ---------------- edge kernel: slot-sorted, segmented wave reduction ----------------

#define LSTRIDE 37   // 35 cols used (32 msg + 3 coord); odd stride -> max 2-way bank alias

__global__ __launch_bounds__(256) void egnn_edge3(
    const float* __restrict__ a, const float* __restrict__ b,
    const float* __restrict__ x,
    const float* __restrict__ ea_s, const int2* __restrict__ sd_s,
    const float* __restrict__ w1, const float* __restrict__ b1,
    const float* __restrict__ w2, const float* __restrict__ b2,
    const float* __restrict__ xw1, const float* __restrict__ xb1,
    const float* __restrict__ xw2, const float* __restrict__ xb2,
    float* __restrict__ agg, float* __restrict__ dxb)
{
    __shared__ float lds[256 * LSTRIDE];
    __shared__ int s_start[4][66];
    __shared__ int s_dstv[4][64];
    __shared__ int s_nseg[4];

    int tid = threadIdx.x;
    int w = tid >> 6, lane = tid & 63;
    int slot = blockIdx.x * 256 + tid;          // grid exact: NE = 6250*256

    int2 sd = sd_s[slot];
    int s = sd.x, d = sd.y;

    // hid = b1 + a[src] + b[dst]   (per-node pre-projections replace 2048 FMA/edge)
    float hid[H];
    const float4* av = (const float4*)(a + (size_t)s * H);
    const float4* bv = (const float4*)(b + (size_t)d * H);
    #pragma unroll
    for (int k4 = 0; k4 < H / 4; ++k4) {
        F4 ua, ub; ua.v = av[k4]; ub.v = bv[k4];
        #pragma unroll
        for (int jj = 0; jj < 4; ++jj)
            hid[4*k4+jj] = b1[4*k4+jj] + ua.f[jj] + ub.f[jj];
    }

    // + ea_s @ W1[rows 64..79]   (coalesced slot-ordered read)
    const float4* eav = (const float4*)(ea_s + (size_t)slot * ED);
    #pragma unroll 1
    for (int j4 = 0; j4 < ED / 4; ++j4)
        acc4(hid, eav[j4], w1 + (2 * H + j4 * 4) * H);

    // + dist * W1[row 80]
    float xi0 = x[3*s+0], xi1 = x[3*s+1], xi2 = x[3*s+2];
    float xj0 = x[3*d+0], xj1 = x[3*d+1], xj2 = x[3*d+2];
    float d0 = xj0 - xi0, d1 = xj1 - xi1, d2 = xj2 - xi2;
    float sq = d0*d0 + d1*d1 + d2*d2;
    float dist = sqrtf(sq + 1e-9f);
    {
        const float* wl = w1 + (2 * H + ED) * H;
        #pragma unroll
        for (int k = 0; k < H; ++k) hid[k] = fmaf(dist, wl[k], hid[k]);
    }

    // SiLU + second linear -> m
    float m[H];
    #pragma unroll
    for (int k = 0; k < H; ++k) m[k] = b2[k];
    #pragma unroll
    for (int j = 0; j < H; ++j) {
        float v = silu_f(hid[j]);
        const float* ww = w2 + j * H;
        #pragma unroll
        for (int k = 0; k < H; ++k) m[k] = fmaf(v, ww[k], m[k]);
    }

    // phi_x -> gate -> coord message
    float gh[H];
    #pragma unroll
    for (int k = 0; k < H; ++k) gh[k] = xb1[k];
    #pragma unroll
    for (int j = 0; j < H; ++j) {
        float v = m[j];
        const float* ww = xw1 + j * H;
        #pragma unroll
        for (int k = 0; k < H; ++k) gh[k] = fmaf(v, ww[k], gh[k]);
    }
    float gate = xb2[0];
    #pragma unroll
    for (int j = 0; j < H; ++j) gate = fmaf(silu_f(gh[j]), xw2[j], gate);
    float scale = gate / (sqrtf(sq) + 1e-9f);

    // stash row in LDS
    float* row = &lds[tid * LSTRIDE];
    #pragma unroll
    for (int k = 0; k < H; ++k) row[k] = m[k];
    row[32] = d0 * scale; row[33] = d1 * scale; row[34] = d2 * scale;

    // segment boundaries within this wave (dst sorted over slots)
    int dprev = __shfl_up(d, 1, 64);
    bool flag = (lane == 0) || (d != dprev);
    unsigned long long ball = __ballot(flag);
    unsigned long long mask_le = (lane == 63) ? ~0ull : ((1ull << (lane + 1)) - 1ull);
    int segid = __popcll(ball & mask_le) - 1;
    if (flag) { s_start[w][segid] = lane; s_dstv[w][segid] = d; }
    if (lane == 0) {
        int ns = __popcll(ball);
        s_start[w][ns] = 64;
        s_nseg[w] = ns;
    }
    __syncthreads();

    // segment sums -> row atomics (avg ~3 segs/wave -> ~2.6M atomics vs 56M naive)
    int nseg = s_nseg[w];
    const float* wrows = &lds[(w * 64) * LSTRIDE];
    int sub = lane >> 5, col = lane & 31;
    #pragma unroll 1
    for (int sg = sub; sg < nseg; sg += 2) {
        int r0 = s_start[w][sg], r1 = s_start[w][sg + 1];
        float v = 0.0f;
        #pragma unroll 1
        for (int r = r0; r < r1; ++r) v += wrows[r * LSTRIDE + col];
        unsafeAtomicAdd(&agg[(size_t)s_dstv[w][sg] * H + col], v);
    }
    #pragma unroll 1
    for (int j = lane; j < nseg * 4; j += 64) {
        int sg = j >> 2, c = j & 3;
        if (c < 3) {
            int r0 = s_start[w][sg], r1 = s_start[w][sg + 1];
            float v = 0.0f;
            #pragma unroll 1
            for (int r = r0; r < r1; ++r) v += wrows[r * LSTRIDE + 32 + c];
            unsafeAtomicAdd(&dxb[(size_t)s_dstv[w][sg] * 4 + c], v);
        }
    }
}

// ---------------- node kernel: phi_h + LN + x update + next-layer a/b ----------------

__global__ __launch_bounds__(256) void egnn_node3(
    const float* __restrict__ h, const float* __restrict__ agg,
    const float* __restrict__ xin, const float* __restrict__ dxb,
    const float* __restrict__ w1, const float* __restrict__ b1,
    const float* __restrict__ w2, const float* __restrict__ b2,
    const float* __restrict__ lng, const float* __restrict__ lnb,
    const float* __restrict__ nxtw1, int last,
    float* __restrict__ hout, float* __restrict__ xout,
    float* __restrict__ aout, float* __restrict__ bout)
{
    int n = blockIdx.x * 256 + threadIdx.x;
    if (n >= NN) return;
    const float4* h4 = (const float4*)(h + (size_t)n * H);
    const float4* a4 = (const float4*)(agg + (size_t)n * H);

    float hv[H];
    float hid[H];
    #pragma unroll
    for (int k = 0; k < H; ++k) hid[k] = b1[k];
    #pragma unroll 1
    for (int j4 = 0; j4 < H / 4; ++j4) {
        F4 u; u.v = h4[j4];
        #pragma unroll
        for (int jj = 0; jj < 4; ++jj) hv[4*j4+jj] = u.f[jj];
        acc4(hid, u.v, w1 + (j4 * 4) * H);
    }
    #pragma unroll 1
    for (int j4 = 0; j4 < H / 4; ++j4)
        acc4(hid, a4[j4], w1 + (H + j4 * 4) * H);

    float dh[H];
    #pragma unroll
    for (int k = 0; k < H; ++k) dh[k] = b2[k];
    #pragma unroll
    for (int j = 0; j < H; ++j) {
        float v = silu_f(hid[j]);
        const float* ww = w2 + j * H;
        #pragma unroll
        for (int k = 0; k < H; ++k) dh[k] = fmaf(v, ww[k], dh[k]);
    }

    float y[H];
    float mu = 0.0f;
    #pragma unroll
    for (int k = 0; k < H; ++k) { y[k] = hv[k] + dh[k]; mu += y[k]; }
    mu *= (1.0f / H);
    float var = 0.0f;
    #pragma unroll
    for (int k = 0; k < H; ++k) { float t = y[k] - mu; var += t * t; }
    var *= (1.0f / H);
    float rstd = rsqrtf(var + 1e-5f);

    float hn[H];
    #pragma unroll
    for (int k = 0; k < H; ++k) hn[k] = (y[k] - mu) * rstd * lng[k] + lnb[k];

    float4* ho4 = (float4*)(hout + (size_t)n * H);
    #pragma unroll
    for (int k4 = 0; k4 < H / 4; ++k4) {
        float4 o;
        o.x = hn[4*k4+0]; o.y = hn[4*k4+1]; o.z = hn[4*k4+2]; o.w = hn[4*k4+3];
        ho4[k4] = o;
    }

    xout[3*n+0] = xin[3*n+0] + dxb[(size_t)n * 4 + 0];
    xout[3*n+1] = xin[3*n+1] + dxb[(size_t)n * 4 + 1];
    xout[3*n+2] = xin[3*n+2] + dxb[(size_t)n * 4 + 2];

    if (!last) {
        float pa[H];
        #pragma unroll
        for (int k = 0; k < H; ++k) pa[k] = 0.0f;
        #pragma unroll 1
        for (int j = 0; j < H; ++j) {
            float v = hn[j];
            const float* ww = nxtw1 + j * H;
            #pragma unroll
            for (int k = 0; k < H; ++k) pa[k] = fmaf(v, ww[k], pa[k]);
        }
        float4* ao4 = (float4*)(aout + (size_t)n * H);
        #pragma unroll
        for (int k4 = 0; k4 < H / 4; ++k4) {
            float4 o;
            o.x = pa[4*k4+0]; o.y = pa[4*k4+1]; o.z = pa[4*k4+2]; o.w = pa[4*k4+3];
            ao4[k4] = o;
        }
        #pragma unroll
        for (int k = 0; k < H; ++k) pa[k] = 0.0f;
        #pragma unroll 1
        for (int j = 0; j < H; ++j) {
            float v = hn[j];
            const float* ww = nxtw1 + (H + j) * H;
            #pragma unroll
            for (int k = 0; k < H; ++k) pa[k] = fmaf(v, ww[k], pa[k]);
        }
        float4* bo4 = (float4*)(bout + (size_t)n * H);
        #pragma unroll
        for (int k4 = 0; k4 < H / 4; ++k4) {
            float4 o;
            o.x = pa[4*k4+0]; o.y = pa[4*k4+1]; o.z = pa[4*k4+2]; o.w = pa[4*k4+3];
            bo4[k4] = o;
        }
    }
}

extern "C" void kernel_launch(void* const* d_in, const int* in_sizes, int n_in,
                              void* d_out, int out_size, void* d_ws, size_t ws_size,
                              hipStream_t stream) {
    const float* node_pos  = (const float*)d_in[0];
    const float* node_feat = (const float*)d_in[1];
    const float* edge_attr = (const float*)d_in[2];
    const float* proj_w    = (const float*)d_in[3];
    const float* proj_b    = (const float*)d_in[4];
    const float* pe_w1     = (const float*)d_in[5];
    const float* pe_b1     = (const float*)d_in[6];
    const float* pe_w2     = (const float*)d_in[7];
    const float* pe_b2     = (const float*)d_in[8];
    const float* ph_w1     = (const float*)d_in[9];
    const float* ph_b1     = (const float*)d_in[10];
    const float* ph_w2     = (const float*)d_in[11];
    const float* ph_b2     = (const float*)d_in[12];
    const float* px_w1     = (const float*)d_in[13];
    const float* px_b1     = (const float*)d_in[14];
    const float* px_w2     = (const float*)d_in[15];
    const float* px_b2     = (const float*)d_in[16];
    const float* ln_g      = (const float*)d_in[17];
    const float* ln_b      = (const float*)d_in[18];
    const int*   eidx      = (const int*)d_in[19];
    const int*   esrc      = eidx;
    const int*   edst      = eidx + NE;

    float* out_h = (float*)d_out;
    float* out_x = out_h + (size_t)NN * H;

    // ---- workspace layout (all offsets multiples of 4 floats -> 16B aligned) ----
    size_t off = 0;
    float* ea_s = (float*)d_ws;               off += (size_t)NE * ED;     // 102.4 MB
    int2*  sd_s = (int2*)((float*)d_ws + off); off += (size_t)NE * 2;     // 12.8 MB
    float* abuf = (float*)d_ws + off;         off += (size_t)NN * H;
    float* bbuf = (float*)d_ws + off;         off += (size_t)NN * H;
    float* h_a  = (float*)d_ws + off;         off += (size_t)NN * H;
    float* h_b  = (float*)d_ws + off;         off += (size_t)NN * H;
    float* x_a  = (float*)d_ws + off;         off += (size_t)NN * 3;      // 150000 %4==0
    float* x_b  = (float*)d_ws + off;         off += (size_t)NN * 3;
    float* agg  = (float*)d_ws + off;         off += (size_t)NN * H;      // zeroed per layer
    float* dxb  = (float*)d_ws + off;         off += (size_t)NN * 4;      // adjacent to agg
    int*   cnt  = (int*)((float*)d_ws + off); off += NN;
    int*   rs   = (int*)((float*)d_ws + off); off += NN + 4;
    int*   rank = (int*)((float*)d_ws + off); off += NE;
    int*   eid  = (int*)((float*)d_ws + off); off += NE;

    dim3 nblk((NN + 255) / 256), eblk(NE / 256);   // NE = 6250*256 exactly

    // CSR build + permutation (edge_index constant across layers)
    hipMemsetAsync(cnt, 0, NN * sizeof(int), stream);
    k_hist<<<eblk, 256, 0, stream>>>(edst, cnt, rank);
    k_scan<<<1, 1024, 0, stream>>>(cnt, rs);
    k_scatter<<<eblk, 256, 0, stream>>>(edst, rank, rs, eid);
    k_permute<<<eblk, 256, 0, stream>>>(eid, edge_attr, esrc, edst, ea_s, sd_s);

    proj2<<<nblk, 256, 0, stream>>>(node_feat, proj_w, proj_b, pe_w1, h_a, abuf, bbuf);

    const float* hcur = h_a;
    const float* xcur = node_pos;
    float* hbufs[2] = { h_b, h_a };
    float* xbufs[2] = { x_a, x_b };

    for (int l = 0; l < NL; ++l) {
        hipMemsetAsync(agg, 0, (size_t)NN * (H + 4) * sizeof(float), stream);
        egnn_edge3<<<eblk, 256, 0, stream>>>(abuf, bbuf, xcur, ea_s, sd_s,
            pe_w1 + (size_t)l * (2*H + ED + 1) * H, pe_b1 + l * H,
            pe_w2 + (size_t)l * H * H,             pe_b2 + l * H,
            px_w1 + (size_t)l * H * H,             px_b1 + l * H,
            px_w2 + (size_t)l * H,                 px_b2 + l,
            agg, dxb);
        float* ho = (l == NL - 1) ? out_h : hbufs[l & 1];
        float* xo = (l == NL - 1) ? out_x : xbufs[l & 1];
        int last = (l == NL - 1);
        const float* nxtw1 = last ? pe_w1 : (pe_w1 + (size_t)(l + 1) * (2*H + ED + 1) * H);
        egnn_node3<<<nblk, 256, 0, stream>>>(hcur, agg, xcur, dxb,
            ph_w1 + (size_t)l * 2 * H * H, ph_b1 + l * H,
            ph_w2 + (size_t)l * H * H,     ph_b2 + l * H,
            ln_g + l * H, ln_b + l * H,
            nxtw1, last, ho, xo, abuf, bbuf);
        hcur = ho;
        xcur = xo;
    }
}

// Round 5
// 1157.991 us; speedup vs baseline: 10.5796x; 1.1496x over previous
//
#include <hip/hip_runtime.h>
#include <math.h>

#define NN 50000
#define NE 1600000
#define H  32
#define ED 16
#define FIN 23
#define NL 4
#define CPAD 16   // ints per histogram counter (64B line) to cut atomic line contention

union F4 { float4 v; float f[4]; };

__device__ __forceinline__ float silu_f(float v) {
    float e = __expf(-v);
    return v * __builtin_amdgcn_rcpf(1.0f + e);   // |err| ~1ULP of rcp; fine vs 0.86 thr
}

// hid += (4 rows of W) dot (4 input vals in hv4); W rows wave-uniform -> s_load + v_fmac
__device__ __forceinline__ void acc4(float hid[H], float4 hv4, const float* __restrict__ w) {
    F4 u; u.v = hv4;
    #pragma unroll
    for (int jj = 0; jj < 4; ++jj) {
        float v = u.f[jj];
        #pragma unroll
        for (int k = 0; k < H; ++k) hid[k] = fmaf(v, w[jj * H + k], hid[k]);
    }
}

// ---------------- per-layer weight pre-products: W2X = W2@XW1, cvec = b2@XW1+xb1 ----

__global__ __launch_bounds__(256) void k_prep(
    const float* __restrict__ pe_w2, const float* __restrict__ pe_b2,
    const float* __restrict__ px_w1, const float* __restrict__ px_b1,
    float* __restrict__ w2x, float* __restrict__ cvec)
{
    int l = blockIdx.x;
    const float* w2  = pe_w2 + (size_t)l * H * H;
    const float* xw1 = px_w1 + (size_t)l * H * H;
    int tid = threadIdx.x;
    #pragma unroll
    for (int q = 0; q < 4; ++q) {
        int idx = q * 256 + tid;          // 0..1023 = j*32+k
        int j = idx >> 5, k = idx & 31;
        float acc = 0.0f;
        #pragma unroll
        for (int t = 0; t < H; ++t) acc = fmaf(w2[j * H + t], xw1[t * H + k], acc);
        w2x[(size_t)l * H * H + idx] = acc;
    }
    if (tid < H) {
        const float* b2 = pe_b2 + l * H;
        float acc = px_b1[l * H + tid];
        #pragma unroll
        for (int t = 0; t < H; ++t) acc = fmaf(b2[t], xw1[t * H + tid], acc);
        cvec[l * H + tid] = acc;
    }
}

// ---------------- CSR build (once per call) ----------------

__global__ __launch_bounds__(256) void k_hist(
    const int* __restrict__ edst, int* __restrict__ cnt, int* __restrict__ rank)
{
    int e = blockIdx.x * 256 + threadIdx.x;
    if (e >= NE) return;
    rank[e] = atomicAdd(&cnt[(size_t)edst[e] * CPAD], 1);
}

__global__ __launch_bounds__(1024) void k_scan(
    const int* __restrict__ cnt, int* __restrict__ rs)
{
    __shared__ int wsum[16];
    __shared__ int s_carry;
    int t = threadIdx.x;
    int lane = t & 63, wid = t >> 6;
    if (t == 0) s_carry = 0;
    __syncthreads();
    for (int base = 0; base < NN; base += 1024) {
        int i = base + t;
        int v = (i < NN) ? cnt[(size_t)i * CPAD] : 0;
        int incl = v;
        #pragma unroll
        for (int off = 1; off < 64; off <<= 1) {
            int u = __shfl_up(incl, off, 64);
            if (lane >= off) incl += u;
        }
        if (lane == 63) wsum[wid] = incl;
        __syncthreads();
        int wpre = 0;
        #pragma unroll
        for (int w = 0; w < 16; ++w) { int ws = wsum[w]; wpre += (w < wid) ? ws : 0; }
        int carry = s_carry;
        if (i < NN) rs[i] = carry + wpre + incl - v;   // exclusive
        __syncthreads();
        if (t == 1023) s_carry = carry + wpre + incl;
        __syncthreads();
    }
    if (t == 0) rs[NN] = s_carry;
}

__global__ __launch_bounds__(256) void k_scatter(
    const int* __restrict__ edst, const int* __restrict__ rank,
    const int* __restrict__ rs, int* __restrict__ eid)
{
    int e = blockIdx.x * 256 + threadIdx.x;
    if (e >= NE) return;
    eid[rs[edst[e]] + rank[e]] = e;
}

// permute edge_attr + (src,dst) into dst-sorted slot order (once; reused all layers)
__global__ __launch_bounds__(256) void k_permute(
    const int* __restrict__ eid, const float* __restrict__ ea,
    const int* __restrict__ esrc, const int* __restrict__ edst,
    float* __restrict__ ea_s, int2* __restrict__ sd_s)
{
    int slot = blockIdx.x * 256 + threadIdx.x;
    if (slot >= NE) return;
    int e = eid[slot];
    const float4* src4 = (const float4*)(ea + (size_t)e * ED);
    float4* dst4 = (float4*)(ea_s + (size_t)slot * ED);
    #pragma unroll
    for (int j = 0; j < ED / 4; ++j) dst4[j] = src4[j];
    int2 sd; sd.x = esrc[e]; sd.y = edst[e];
    sd_s[slot] = sd;
}

// ---------------- input projection + layer-0 node pre-projections ----------------

__global__ __launch_bounds__(256) void proj2(
    const float* __restrict__ feat, const float* __restrict__ W,
    const float* __restrict__ bias, const float* __restrict__ pew1,
    float* __restrict__ h, float* __restrict__ a, float* __restrict__ b)
{
    int n = blockIdx.x * 256 + threadIdx.x;
    if (n >= NN) return;
    float acc[H];
    #pragma unroll
    for (int k = 0; k < H; ++k) acc[k] = bias[k];
    #pragma unroll 1
    for (int j = 0; j < FIN; ++j) {
        float v = feat[n * FIN + j];
        const float* w = W + j * H;
        #pragma unroll
        for (int k = 0; k < H; ++k) acc[k] = fmaf(v, w[k], acc[k]);
    }
    float4* h4 = (float4*)(h + (size_t)n * H);
    #pragma unroll
    for (int k4 = 0; k4 < H / 4; ++k4) {
        float4 o;
        o.x = acc[4*k4+0]; o.y = acc[4*k4+1]; o.z = acc[4*k4+2]; o.w = acc[4*k4+3];
        h4[k4] = o;
    }
    float pa[H];
    #pragma unroll
    for (int k = 0; k < H; ++k) pa[k] = 0.0f;
    #pragma unroll 1
    for (int j = 0; j < H; ++j) {
        float v = acc[j];
        const float* w = pew1 + j * H;
        #pragma unroll
        for (int k = 0; k < H; ++k) pa[k] = fmaf(v, w[k], pa[k]);
    }
    float4* a4 = (float4*)(a + (size_t)n * H);
    #pragma unroll
    for (int k4 = 0; k4 < H / 4; ++k4) {
        float4 o;
        o.x = pa[4*k4+0]; o.y = pa[4*k4+1]; o.z = pa[4*k4+2]; o.w = pa[4*k4+3];
        a4[k4] = o;
    }
    #pragma unroll
    for (int k = 0; k < H; ++k) pa[k] = 0.0f;
    #pragma unroll 1
    for (int j = 0; j < H; ++j) {
        float v = acc[j];
        const float* w = pew1 + (H + j) * H;
        #pragma unroll
        for (int k = 0; k < H; ++k) pa[k] = fmaf(v, w[k], pa[k]);
    }
    float4* b4 = (float4*)(b + (size_t)n * H);
    #pragma unroll
    for (int k4 = 0; k4 < H / 4; ++k4) {
        float4 o;
        o.x = pa[4*k4+0]; o.y = pa[4*k4+1]; o.z = pa[4*k4+2]; o.w = pa[4*k4+3];
        b4[k4] = o;
    }
}

// ---------------- edge kernel: scatter silu(hid); gate via precomputed W2X ----------

#define LSTRIDE 37   // 35 cols used (32 s + 3 coord); odd stride -> max 2-way bank alias

__global__ __launch_bounds__(256) void egnn_edge4(
    const float* __restrict__ a, const float* __restrict__ b,
    const float* __restrict__ x,
    const float* __restrict__ ea_s, const int2* __restrict__ sd_s,
    const float* __restrict__ w1, const float* __restrict__ b1,
    const float* __restrict__ w2x, const float* __restrict__ cvec,
    const float* __restrict__ xw2, const float* __restrict__ xb2,
    float* __restrict__ agg, float* __restrict__ dxb)
{
    __shared__ float lds[256 * LSTRIDE];
    __shared__ int s_start[4][66];
    __shared__ int s_dstv[4][64];
    __shared__ int s_nseg[4];

    int tid = threadIdx.x;
    int w = tid >> 6, lane = tid & 63;
    int slot = blockIdx.x * 256 + tid;          // grid exact: NE = 6250*256

    int2 sd = sd_s[slot];
    int s = sd.x, d = sd.y;

    // hid = b1 + a[src] + b[dst]
    float hid[H];
    const float4* av = (const float4*)(a + (size_t)s * H);
    const float4* bv = (const float4*)(b + (size_t)d * H);
    #pragma unroll
    for (int k4 = 0; k4 < H / 4; ++k4) {
        F4 ua, ub; ua.v = av[k4]; ub.v = bv[k4];
        #pragma unroll
        for (int jj = 0; jj < 4; ++jj)
            hid[4*k4+jj] = b1[4*k4+jj] + ua.f[jj] + ub.f[jj];
    }

    // + ea_s @ W1[rows 64..79]   (coalesced slot-ordered read)
    const float4* eav = (const float4*)(ea_s + (size_t)slot * ED);
    #pragma unroll 1
    for (int j4 = 0; j4 < ED / 4; ++j4)
        acc4(hid, eav[j4], w1 + (2 * H + j4 * 4) * H);

    // + dist * W1[row 80]
    float xi0 = x[3*s+0], xi1 = x[3*s+1], xi2 = x[3*s+2];
    float xj0 = x[3*d+0], xj1 = x[3*d+1], xj2 = x[3*d+2];
    float d0 = xj0 - xi0, d1 = xj1 - xi1, d2 = xj2 - xi2;
    float sq = d0*d0 + d1*d1 + d2*d2;
    float dist = __builtin_amdgcn_sqrtf(sq + 1e-9f);
    {
        const float* wl = w1 + (2 * H + ED) * H;
        #pragma unroll
        for (int k = 0; k < H; ++k) hid[k] = fmaf(dist, wl[k], hid[k]);
    }

    // s = silu(hid); gh = cvec + s @ W2X  (W2X = W2@XW1 precomputed)
    float sarr[H];
    float gh[H];
    #pragma unroll
    for (int k = 0; k < H; ++k) gh[k] = cvec[k];
    #pragma unroll
    for (int j = 0; j < H; ++j) {
        float v = silu_f(hid[j]);
        sarr[j] = v;
        const float* ww = w2x + j * H;
        #pragma unroll
        for (int k = 0; k < H; ++k) gh[k] = fmaf(v, ww[k], gh[k]);
    }

    float gate = xb2[0];
    #pragma unroll
    for (int j = 0; j < H; ++j) gate = fmaf(silu_f(gh[j]), xw2[j], gate);
    float scale = gate * __builtin_amdgcn_rcpf(__builtin_amdgcn_sqrtf(sq) + 1e-9f);

    // stash row in LDS: 32 silu values + 3 coord msgs
    float* row = &lds[tid * LSTRIDE];
    #pragma unroll
    for (int k = 0; k < H; ++k) row[k] = sarr[k];
    row[32] = d0 * scale; row[33] = d1 * scale; row[34] = d2 * scale;

    // segment boundaries within this wave (dst sorted over slots)
    int dprev = __shfl_up(d, 1, 64);
    bool flag = (lane == 0) || (d != dprev);
    unsigned long long ball = __ballot(flag);
    unsigned long long mask_le = (lane == 63) ? ~0ull : ((1ull << (lane + 1)) - 1ull);
    int segid = __popcll(ball & mask_le) - 1;
    if (flag) { s_start[w][segid] = lane; s_dstv[w][segid] = d; }
    if (lane == 0) {
        int ns = __popcll(ball);
        s_start[w][ns] = 64;
        s_nseg[w] = ns;
    }
    __syncthreads();

    // segment sums -> row atomics (avg ~3 segs/wave)
    int nseg = s_nseg[w];
    const float* wrows = &lds[(w * 64) * LSTRIDE];
    int sub = lane >> 5, col = lane & 31;
    #pragma unroll 1
    for (int sg = sub; sg < nseg; sg += 2) {
        int r0 = s_start[w][sg], r1 = s_start[w][sg + 1];
        float v = 0.0f;
        #pragma unroll 1
        for (int r = r0; r < r1; ++r) v += wrows[r * LSTRIDE + col];
        unsafeAtomicAdd(&agg[(size_t)s_dstv[w][sg] * H + col], v);
    }
    #pragma unroll 1
    for (int j = lane; j < nseg * 4; j += 64) {
        int sg = j >> 2, c = j & 3;
        if (c < 3) {
            int r0 = s_start[w][sg], r1 = s_start[w][sg + 1];
            float v = 0.0f;
            #pragma unroll 1
            for (int r = r0; r < r1; ++r) v += wrows[r * LSTRIDE + 32 + c];
            unsafeAtomicAdd(&dxb[(size_t)s_dstv[w][sg] * 4 + c], v);
        }
    }
}

// ---------------- node kernel: finish agg (deg*b2 + agg_s@W2), phi_h, LN, x, a/b ----

__global__ __launch_bounds__(256) void egnn_node4(
    const float* __restrict__ h, const float* __restrict__ agg,
    const float* __restrict__ xin, const float* __restrict__ dxb,
    const int* __restrict__ rs,
    const float* __restrict__ ew2, const float* __restrict__ eb2,  // pe_w2[l], pe_b2[l]
    const float* __restrict__ w1, const float* __restrict__ b1,
    const float* __restrict__ w2, const float* __restrict__ b2,
    const float* __restrict__ lng, const float* __restrict__ lnb,
    const float* __restrict__ nxtw1, int last,
    float* __restrict__ hout, float* __restrict__ xout,
    float* __restrict__ aout, float* __restrict__ bout)
{
    int n = blockIdx.x * 256 + threadIdx.x;
    if (n >= NN) return;
    const float4* h4 = (const float4*)(h + (size_t)n * H);
    const float4* a4 = (const float4*)(agg + (size_t)n * H);

    // finish aggregation: ma = deg*b2_e + agg_s @ W2_e
    float degf = (float)(rs[n + 1] - rs[n]);
    float ma[H];
    #pragma unroll
    for (int k = 0; k < H; ++k) ma[k] = degf * eb2[k];
    #pragma unroll 1
    for (int j4 = 0; j4 < H / 4; ++j4)
        acc4(ma, a4[j4], ew2 + (j4 * 4) * H);

    float hv[H];
    float hid[H];
    #pragma unroll
    for (int k = 0; k < H; ++k) hid[k] = b1[k];
    #pragma unroll 1
    for (int j4 = 0; j4 < H / 4; ++j4) {
        F4 u; u.v = h4[j4];
        #pragma unroll
        for (int jj = 0; jj < 4; ++jj) hv[4*j4+jj] = u.f[jj];
        acc4(hid, u.v, w1 + (j4 * 4) * H);
    }
    #pragma unroll
    for (int j = 0; j < H; ++j) {
        float v = ma[j];
        const float* ww = w1 + (H + j) * H;
        #pragma unroll
        for (int k = 0; k < H; ++k) hid[k] = fmaf(v, ww[k], hid[k]);
    }

    float dh[H];
    #pragma unroll
    for (int k = 0; k < H; ++k) dh[k] = b2[k];
    #pragma unroll
    for (int j = 0; j < H; ++j) {
        float v = silu_f(hid[j]);
        const float* ww = w2 + j * H;
        #pragma unroll
        for (int k = 0; k < H; ++k) dh[k] = fmaf(v, ww[k], dh[k]);
    }

    float y[H];
    float mu = 0.0f;
    #pragma unroll
    for (int k = 0; k < H; ++k) { y[k] = hv[k] + dh[k]; mu += y[k]; }
    mu *= (1.0f / H);
    float var = 0.0f;
    #pragma unroll
    for (int k = 0; k < H; ++k) { float t = y[k] - mu; var += t * t; }
    var *= (1.0f / H);
    float rstd = rsqrtf(var + 1e-5f);

    float hn[H];
    #pragma unroll
    for (int k = 0; k < H; ++k) hn[k] = (y[k] - mu) * rstd * lng[k] + lnb[k];

    float4* ho4 = (float4*)(hout + (size_t)n * H);
    #pragma unroll
    for (int k4 = 0; k4 < H / 4; ++k4) {
        float4 o;
        o.x = hn[4*k4+0]; o.y = hn[4*k4+1]; o.z = hn[4*k4+2]; o.w = hn[4*k4+3];
        ho4[k4] = o;
    }

    xout[3*n+0] = xin[3*n+0] + dxb[(size_t)n * 4 + 0];
    xout[3*n+1] = xin[3*n+1] + dxb[(size_t)n * 4 + 1];
    xout[3*n+2] = xin[3*n+2] + dxb[(size_t)n * 4 + 2];

    if (!last) {
        float pa[H];
        #pragma unroll
        for (int k = 0; k < H; ++k) pa[k] = 0.0f;
        #pragma unroll 1
        for (int j = 0; j < H; ++j) {
            float v = hn[j];
            const float* ww = nxtw1 + j * H;
            #pragma unroll
            for (int k = 0; k < H; ++k) pa[k] = fmaf(v, ww[k], pa[k]);
        }
        float4* ao4 = (float4*)(aout + (size_t)n * H);
        #pragma unroll
        for (int k4 = 0; k4 < H / 4; ++k4) {
            float4 o;
            o.x = pa[4*k4+0]; o.y = pa[4*k4+1]; o.z = pa[4*k4+2]; o.w = pa[4*k4+3];
            ao4[k4] = o;
        }
        #pragma unroll
        for (int k = 0; k < H; ++k) pa[k] = 0.0f;
        #pragma unroll 1
        for (int j = 0; j < H; ++j) {
            float v = hn[j];
            const float* ww = nxtw1 + (H + j) * H;
            #pragma unroll
            for (int k = 0; k < H; ++k) pa[k] = fmaf(v, ww[k], pa[k]);
        }
        float4* bo4 = (float4*)(bout + (size_t)n * H);
        #pragma unroll
        for (int k4 = 0; k4 < H / 4; ++k4) {
            float4 o;
            o.x = pa[4*k4+0]; o.y = pa[4*k4+1]; o.z = pa[4*k4+2]; o.w = pa[4*k4+3];
            bo4[k4] = o;
        }
    }
}

extern "C" void kernel_launch(void* const* d_in, const int* in_sizes, int n_in,
                              void* d_out, int out_size, void* d_ws, size_t ws_size,
                              hipStream_t stream) {
    const float* node_pos  = (const float*)d_in[0];
    const float* node_feat = (const float*)d_in[1];
    const float* edge_attr = (const float*)d_in[2];
    const float* proj_w    = (const float*)d_in[3];
    const float* proj_b    = (const float*)d_in[4];
    const float* pe_w1     = (const float*)d_in[5];
    const float* pe_b1     = (const float*)d_in[6];
    const float* pe_w2     = (const float*)d_in[7];
    const float* pe_b2     = (const float*)d_in[8];
    const float* ph_w1     = (const float*)d_in[9];
    const float* ph_b1     = (const float*)d_in[10];
    const float* ph_w2     = (const float*)d_in[11];
    const float* ph_b2     = (const float*)d_in[12];
    const float* px_w1     = (const float*)d_in[13];
    const float* px_b1     = (const float*)d_in[14];
    const float* px_w2     = (const float*)d_in[15];
    const float* px_b2     = (const float*)d_in[16];
    const float* ln_g      = (const float*)d_in[17];
    const float* ln_b      = (const float*)d_in[18];
    const int*   eidx      = (const int*)d_in[19];
    const int*   esrc      = eidx;
    const int*   edst      = eidx + NE;

    float* out_h = (float*)d_out;
    float* out_x = out_h + (size_t)NN * H;

    // ---- workspace layout (offsets in floats; all 16B aligned) ----
    size_t off = 0;
    float* ea_s = (float*)d_ws;                off += (size_t)NE * ED;     // 102.4 MB
    int2*  sd_s = (int2*)((float*)d_ws + off); off += (size_t)NE * 2;      // 12.8 MB
    float* abuf = (float*)d_ws + off;          off += (size_t)NN * H;
    float* bbuf = (float*)d_ws + off;          off += (size_t)NN * H;
    float* h_a  = (float*)d_ws + off;          off += (size_t)NN * H;
    float* h_b  = (float*)d_ws + off;          off += (size_t)NN * H;
    float* x_a  = (float*)d_ws + off;          off += (size_t)NN * 3;
    float* x_b  = (float*)d_ws + off;          off += (size_t)NN * 3;
    float* agg  = (float*)d_ws + off;          off += (size_t)NN * H;      // zeroed per layer
    float* dxb  = (float*)d_ws + off;          off += (size_t)NN * 4;      // adjacent to agg
    float* w2x  = (float*)d_ws + off;          off += (size_t)NL * H * H;
    float* cvec = (float*)d_ws + off;          off += (size_t)NL * H;
    int*   cnt  = (int*)((float*)d_ws + off);  off += (size_t)NN * CPAD;   // padded counters
    int*   rs   = (int*)((float*)d_ws + off);  off += NN + 4;
    int*   rank = (int*)((float*)d_ws + off);  off += NE;
    int*   eid  = (int*)((float*)d_ws + off);  off += NE;

    dim3 nblk((NN + 255) / 256), eblk(NE / 256);   // NE = 6250*256 exactly

    // CSR build + permutation (edge_index constant across layers) + weight preproducts
    hipMemsetAsync(cnt, 0, (size_t)NN * CPAD * sizeof(int), stream);
    k_hist<<<eblk, 256, 0, stream>>>(edst, cnt, rank);
    k_scan<<<1, 1024, 0, stream>>>(cnt, rs);
    k_scatter<<<eblk, 256, 0, stream>>>(edst, rank, rs, eid);
    k_permute<<<eblk, 256, 0, stream>>>(eid, edge_attr, esrc, edst, ea_s, sd_s);
    k_prep<<<dim3(NL), 256, 0, stream>>>(pe_w2, pe_b2, px_w1, px_b1, w2x, cvec);

    proj2<<<nblk, 256, 0, stream>>>(node_feat, proj_w, proj_b, pe_w1, h_a, abuf, bbuf);

    const float* hcur = h_a;
    const float* xcur = node_pos;
    float* hbufs[2] = { h_b, h_a };
    float* xbufs[2] = { x_a, x_b };

    for (int l = 0; l < NL; ++l) {
        hipMemsetAsync(agg, 0, (size_t)NN * (H + 4) * sizeof(float), stream);
        egnn_edge4<<<eblk, 256, 0, stream>>>(abuf, bbuf, xcur, ea_s, sd_s,
            pe_w1 + (size_t)l * (2*H + ED + 1) * H, pe_b1 + l * H,
            w2x + (size_t)l * H * H,               cvec + l * H,
            px_w2 + (size_t)l * H,                 px_b2 + l,
            agg, dxb);
        float* ho = (l == NL - 1) ? out_h : hbufs[l & 1];
        float* xo = (l == NL - 1) ? out_x : xbufs[l & 1];
        int last = (l == NL - 1);
        const float* nxtw1 = last ? pe_w1 : (pe_w1 + (size_t)(l + 1) * (2*H + ED + 1) * H);
        egnn_node4<<<nblk, 256, 0, stream>>>(hcur, agg, xcur, dxb, rs,
            pe_w2 + (size_t)l * H * H, pe_b2 + l * H,
            ph_w1 + (size_t)l * 2 * H * H, ph_b1 + l * H,
            ph_w2 + (size_t)l * H * H,     ph_b2 + l * H,
            ln_g + l * H, ln_b + l * H,
            nxtw1, last, ho, xo, abuf, bbuf);
        hcur = ho;
        xcur = xo;
    }
}